// Round 11
// baseline (816.342 us; speedup 1.0000x reference)
//
#include <hip/hip_runtime.h>
#include <stdint.h>

typedef __bf16   bf16x8  __attribute__((ext_vector_type(8)));
typedef float    f32x4   __attribute__((ext_vector_type(4)));
typedef uint16_t u16x8   __attribute__((ext_vector_type(8)));

using as1_cvp = const __attribute__((address_space(1))) void*;
using as3_vp  = __attribute__((address_space(3))) void*;

__device__ __forceinline__ uint16_t f2bf(float f) {
    uint32_t u = __float_as_uint(f);
    u += 0x7FFF + ((u >> 16) & 1);          // RNE
    return (uint16_t)(u >> 16);
}

__device__ __forceinline__ void gload16(const void* g, void* l) {
    __builtin_amdgcn_global_load_lds((as1_cvp)g, (as3_vp)l, 16, 0, 0);
}

#define MFMA16(a, b, c) __builtin_amdgcn_mfma_f32_16x16x32_bf16((a), (b), (c), 0, 0, 0)

// ---------------------------------------------------------------- f32 -> bf16
__global__ __launch_bounds__(256)
void cvt_bf16(const float* __restrict__ in, uint16_t* __restrict__ out, int n8)
{
    int i = blockIdx.x * 256 + threadIdx.x;
    if (i >= n8) return;
    const float4* p = reinterpret_cast<const float4*>(in) + (size_t)i * 2;
    float4 a = p[0], b = p[1];
    u16x8 o;
    o[0] = f2bf(a.x); o[1] = f2bf(a.y); o[2] = f2bf(a.z); o[3] = f2bf(a.w);
    o[4] = f2bf(b.x); o[5] = f2bf(b.y); o[6] = f2bf(b.z); o[7] = f2bf(b.w);
    reinterpret_cast<u16x8*>(out)[i] = o;
}

// ---- merged 5-matrix convert (one launch, saves ~34us of launch overhead)
__global__ __launch_bounds__(256)
void cvt5(const float* __restrict__ s0, const float* __restrict__ s1,
          const float* __restrict__ s2, const float* __restrict__ s3,
          const float* __restrict__ s4,
          uint16_t* __restrict__ d0, uint16_t* __restrict__ d1,
          uint16_t* __restrict__ d2, uint16_t* __restrict__ d3,
          uint16_t* __restrict__ d4)
{
    const int r = blockIdx.x >> 13;
    const float*  src = (r == 0) ? s0 : (r == 1) ? s1 : (r == 2) ? s2
                       : (r == 3) ? s3 : s4;
    uint16_t*     dst = (r == 0) ? d0 : (r == 1) ? d1 : (r == 2) ? d2
                       : (r == 3) ? d3 : d4;
    const int i = (blockIdx.x & 8191) * 256 + threadIdx.x;
    const float4* p = reinterpret_cast<const float4*>(src) + (size_t)i * 2;
    float4 a = p[0], b = p[1];
    u16x8 o;
    o[0] = f2bf(a.x); o[1] = f2bf(a.y); o[2] = f2bf(a.z); o[3] = f2bf(a.w);
    o[4] = f2bf(b.x); o[5] = f2bf(b.y); o[6] = f2bf(b.z); o[7] = f2bf(b.w);
    reinterpret_cast<u16x8*>(dst)[i] = o;
}

// ---------------------------------------------------------------------------
// 128x128 GEMM, 2 blocks/CU (m114 cross-block overlap): r6's pipelined-
// fragment discipline at 64KB LDS so TWO independent blocks co-reside per
// CU — one block's MFMA fills the other's barrier/wait gaps (r10 analysis:
// 2300 cyc/tile of lockstep-exposed stall at 1 block/CU).
// C = A*Bt^T + bias, bf16 operands. 4 waves (2M x 2N), per-wave 64x64
// (acc[4][4]). BK=64 as two K-halves of 32; 64B LDS rows, 16B block
// ^= (row>>1)&3 (proven 0-conflict). 2 phases/tile:
//  ph0: stage kh1(t+1); read kh0 frags (certified); prefetch kh1 frags
//       (counted-lgkm, fly under MFMA); MFMA kh0; barrier.
//  ph1: stage kh0(t+2); MFMA kh1; vmcnt; barrier.
// vmcnt audit (in-order, 4 loads/phase): at ph1(t) queue = kh1(t+1)[4],
// kh0(t+2)[4] (+ leftover kh0(t+1)[4] completed here) -> vmcnt(4)
// completes ALL of tile t+1. Prologue: 12 loads, vmcnt(4) certifies
// kh0(0)+kh1(0). Tail t>=NT-2: drain 0. WAR: every stage slot has >=1
// barrier after its last read (checked per slot/tile parity).
// L3 holds A+B (64MB) so the 4x block count costs L3 hits, not HBM.
// ---------------------------------------------------------------------------
template <int OUT_BF16>
__global__ __launch_bounds__(256, 2)
void gemm128(const uint16_t* __restrict__ A, const uint16_t* __restrict__ Bt,
             const float* __restrict__ bias, void* __restrict__ Cout,
             int M, int N, int K)
{
    __shared__ uint16_t lds[32768];        // 64KB: [buf][kh] x (A 128x32 | B 128x32)
    const int NT = K >> 6;                 // K-tiles of 64

    int bid = blockIdx.x;
    bid = (bid & 7) * 128 + (bid >> 3);    // XCD-aware swizzle (nwg=1024, %8==0)
    const int bx = bid & 31, by = bid >> 5;
    const int rb = by * 128, cb = bx * 128;

    const int tid  = threadIdx.x;
    const int w    = tid >> 6;             // 0..3
    const int lane = tid & 63;
    const int g    = lane >> 4;
    const int l16  = lane & 15;
    const int wm   = w >> 1;               // 0..1
    const int wn   = w & 1;                // 0..1
    const int srow = lane >> 2;            // stage: 4 lanes per 64B row
    const int sblk = lane & 3;             // stage: 16B block within row

    f32x4 acc[4][4] = {};

    // one unit = 128 rows x 32 k (8KB A + 8KB B per (buf,kh) slot)
    auto stageA = [&](int buf, int kh, int kbase) {
#pragma unroll
        for (int i = 0; i < 2; ++i) {
            const int row = i * 64 + w * 16 + srow;
            const uint16_t* src = A + (size_t)(rb + row) * K + kbase
                                    + ((sblk ^ ((row >> 1) & 3)) << 3);
            gload16(src, &lds[(buf * 2 + kh) * 8192 + i * 2048 + w * 512]);
        }
    };
    auto stageB = [&](int buf, int kh, int kbase) {
#pragma unroll
        for (int i = 0; i < 2; ++i) {
            const int row = i * 64 + w * 16 + srow;
            const uint16_t* src = Bt + (size_t)(cb + row) * K + kbase
                                     + ((sblk ^ ((row >> 1) & 3)) << 3);
            gload16(src, &lds[(buf * 2 + kh) * 8192 + 4096 + i * 2048 + w * 512]);
        }
    };

    auto readA = [&](int base, bf16x8* dst) {
#pragma unroll
        for (int mi = 0; mi < 4; ++mi) {
            const int r = wm * 64 + mi * 16 + l16;
            dst[mi] = *reinterpret_cast<const bf16x8*>(
                &lds[base + r * 32 + ((g ^ ((r >> 1) & 3)) << 3)]);
        }
    };
    auto readB = [&](int base, bf16x8* dst) {
#pragma unroll
        for (int n = 0; n < 4; ++n) {
            const int c = wn * 64 + n * 16 + l16;
            dst[n] = *reinterpret_cast<const bf16x8*>(
                &lds[base + 4096 + c * 32 + ((g ^ ((c >> 1) & 3)) << 3)]);
        }
    };

    auto mfma16 = [&](const bf16x8* af, const bf16x8* bf) {
        __builtin_amdgcn_s_setprio(1);
#pragma unroll
        for (int mi = 0; mi < 4; ++mi)
#pragma unroll
            for (int n = 0; n < 4; ++n)
                acc[mi][n] = MFMA16(af[mi], bf[n], acc[mi][n]);
        __builtin_amdgcn_s_setprio(0);
    };

    // ---- prologue: kh0(0),kh1(0),kh0(1) = 12 loads; vmcnt(4) -> tile 0 landed
    stageA(0, 0, 0);  stageB(0, 0, 0);
    stageA(0, 1, 32); stageB(0, 1, 32);
    stageA(1, 0, 64); stageB(1, 0, 64);
    asm volatile("s_waitcnt vmcnt(4)" ::: "memory");
    __builtin_amdgcn_s_barrier();

    for (int t = 0; t < NT; ++t) {
        const int cur = t & 1, nxt = cur ^ 1;
        const int b0 = (cur * 2 + 0) * 8192;
        const int b1 = (cur * 2 + 1) * 8192;
        bf16x8 af0[4], bf0[4], af1[4], bf1[4];

        // ---- ph0: stage kh1(t+1); read kh0; prefetch kh1; MFMA kh0
        if (t + 1 < NT) { stageA(nxt, 1, (t + 1) * 64 + 32);
                          stageB(nxt, 1, (t + 1) * 64 + 32); }
        readA(b0, af0); readB(b0, bf0);
        readA(b1, af1); readB(b1, bf1);    // counted-lgkm: flies under MFMA
        mfma16(af0, bf0);
        __builtin_amdgcn_sched_barrier(0);
        __builtin_amdgcn_s_barrier();

        // ---- ph1: stage kh0(t+2); MFMA kh1; tile-boundary vmcnt
        if (t + 2 < NT) { stageA(cur, 0, (t + 2) * 64);
                          stageB(cur, 0, (t + 2) * 64); }
        mfma16(af1, bf1);
        __builtin_amdgcn_sched_barrier(0);
        if (t >= NT - 2) asm volatile("s_waitcnt vmcnt(0)" ::: "memory");
        else             asm volatile("s_waitcnt vmcnt(4)" ::: "memory");
        __builtin_amdgcn_s_barrier();
    }

    // ---- epilogue (16x16 C/D layout: col = l16, row = 4g + r)
    float bv[4];
#pragma unroll
    for (int n = 0; n < 4; ++n) bv[n] = bias[cb + wn * 64 + n * 16 + l16];

#pragma unroll
    for (int m = 0; m < 4; ++m) {
#pragma unroll
        for (int n = 0; n < 4; ++n) {
            const int col = cb + wn * 64 + n * 16 + l16;
#pragma unroll
            for (int r = 0; r < 4; ++r) {
                const int row = rb + wm * 64 + m * 16 + g * 4 + r;
                float v = acc[m][n][r] + bv[n];
                if (OUT_BF16)
                    ((uint16_t*)Cout)[(size_t)row * N + col] = f2bf(v);
                else
                    ((float*)Cout)[(size_t)row * N + col] = v;
            }
        }
    }
}

// ------------------------------------------------------------------ attention
// One block per (bb, hh). 4 waves; wave w owns query rows [16w, 16w+16).
// Unscaled softmax(Q K^T) V, output scattered through the reference's
// cat/transpose/view permutation directly into Y (bf16 [4096 x 4096]).
__global__ __launch_bounds__(256)
void attn_kernel(const uint16_t* __restrict__ Q, const uint16_t* __restrict__ Kg,
                 const uint16_t* __restrict__ V, uint16_t* __restrict__ Y)
{
    const int bid = blockIdx.x;
    const int hh  = bid & 63;
    const int bb  = bid >> 6;
    const int tid = threadIdx.x;
    const int w   = tid >> 6, lane = tid & 63, g = lane >> 4, l16 = lane & 15;

    __shared__ uint16_t Vt[64 * 64];   // V transposed, XOR-swizzled (8 KB)
    __shared__ uint16_t Pl[64 * 64];   // P bf16, XOR-swizzled (8 KB)

    // ---- stage V transposed: Vt[l][k] = V[k][l], swizzle elem k ^= (l&7)<<3
    {
        const int k  = tid >> 2;
        const int l0 = (tid & 3) * 16;
        const uint16_t* src = V + (size_t)(bb * 64 + k) * 4096 + hh * 64 + l0;
        u16x8 v0 = *reinterpret_cast<const u16x8*>(src);
        u16x8 v1 = *reinterpret_cast<const u16x8*>(src + 8);
#pragma unroll
        for (int i = 0; i < 8; ++i) {
            int l = l0 + i;
            Vt[l * 64 + (k ^ ((l & 7) << 3))] = v0[i];
        }
#pragma unroll
        for (int i = 0; i < 8; ++i) {
            int l = l0 + 8 + i;
            Vt[l * 64 + (k ^ ((l & 7) << 3))] = v1[i];
        }
    }

    // ---- S = Q K^T (rows 16w..16w+16, all 64 cols), direct-global fragments
    f32x4 sa[4] = {};
    {
        const uint16_t* qrow = Q + (size_t)(bb * 64 + w * 16 + l16) * 4096 + hh * 64 + g * 8;
        bf16x8 a0 = *reinterpret_cast<const bf16x8*>(qrow);
        bf16x8 a1 = *reinterpret_cast<const bf16x8*>(qrow + 32);
#pragma unroll
        for (int n = 0; n < 4; ++n) {
            const uint16_t* krow = Kg + (size_t)(bb * 64 + n * 16 + l16) * 4096 + hh * 64 + g * 8;
            bf16x8 b0 = *reinterpret_cast<const bf16x8*>(krow);
            bf16x8 b1 = *reinterpret_cast<const bf16x8*>(krow + 32);
            sa[n] = MFMA16(a0, b0, sa[n]);
            sa[n] = MFMA16(a1, b1, sa[n]);
        }
    }

    // ---- softmax (no 1/sqrt(hd) scale, faithful). Row q = 16w + 4g + j;
    // its 64 values live as regs n=0..3 across the 16-lane group (l16).
    float p[4][4];
#pragma unroll
    for (int j = 0; j < 4; ++j) {
        float mx = fmaxf(fmaxf(sa[0][j], sa[1][j]), fmaxf(sa[2][j], sa[3][j]));
        mx = fmaxf(mx, __shfl_xor(mx, 1));
        mx = fmaxf(mx, __shfl_xor(mx, 2));
        mx = fmaxf(mx, __shfl_xor(mx, 4));
        mx = fmaxf(mx, __shfl_xor(mx, 8));
        float s = 0.f;
#pragma unroll
        for (int n = 0; n < 4; ++n) { p[n][j] = __expf(sa[n][j] - mx); s += p[n][j]; }
        s += __shfl_xor(s, 1);
        s += __shfl_xor(s, 2);
        s += __shfl_xor(s, 4);
        s += __shfl_xor(s, 8);
        float inv = 1.0f / s;
#pragma unroll
        for (int n = 0; n < 4; ++n) p[n][j] *= inv;
    }

    // ---- P -> LDS in A-operand-friendly layout (swizzled)
#pragma unroll
    for (int j = 0; j < 4; ++j) {
        const int q = w * 16 + g * 4 + j;
#pragma unroll
        for (int n = 0; n < 4; ++n) {
            const int kcol = n * 16 + l16;
            Pl[q * 64 + (kcol ^ ((q & 7) << 3))] = f2bf(p[n][j]);
        }
    }
    __syncthreads();   // Vt (all threads) + Pl ready

    // ---- O = P V
    f32x4 oa[4] = {};
    {
        const int qr = w * 16 + l16;
        bf16x8 a0 = *reinterpret_cast<const bf16x8*>(&Pl[qr * 64 + ((g * 8)      ^ ((qr & 7) << 3))]);
        bf16x8 a1 = *reinterpret_cast<const bf16x8*>(&Pl[qr * 64 + ((32 + g * 8) ^ ((qr & 7) << 3))]);
#pragma unroll
        for (int n = 0; n < 4; ++n) {
            const int vr = n * 16 + l16;
            bf16x8 b0 = *reinterpret_cast<const bf16x8*>(&Vt[vr * 64 + ((g * 8)      ^ ((vr & 7) << 3))]);
            bf16x8 b1 = *reinterpret_cast<const bf16x8*>(&Vt[vr * 64 + ((32 + g * 8) ^ ((vr & 7) << 3))]);
            oa[n] = MFMA16(a0, b0, oa[n]);
            oa[n] = MFMA16(a1, b1, oa[n]);
        }
    }

    // ---- permuted store: Ostd[bb,hh,qq,ll] -> Y[b, s, h*64 + l]
#pragma unroll
    for (int n = 0; n < 4; ++n) {
        const int ll = n * 16 + l16;
#pragma unroll
        for (int r = 0; r < 4; ++r) {
            const int qq = w * 16 + g * 4 + r;
            const int b_ = (bb >> 1) + ((ll >= 32) ? 32 : 0);
            const int s_ = ((bb & 1) << 5) + (qq >> 1);
            const int h_ = ((qq & 1) << 5) + (hh >> 1);
            const int l_ = ((hh & 1) << 5) + (ll & 31);
            Y[(size_t)(b_ * 64 + s_) * 4096 + h_ * 64 + l_] = f2bf(oa[n][r]);
        }
    }
}

// ----------------------------------------------------------------------------
extern "C" void kernel_launch(void* const* d_in, const int* in_sizes, int n_in,
                              void* d_out, int out_size, void* d_ws, size_t ws_size,
                              hipStream_t stream)
{
    (void)in_sizes; (void)n_in; (void)out_size;

    const float* x  = (const float*)d_in[0];
    const float* Wq = (const float*)d_in[1];
    const float* bq = (const float*)d_in[2];
    const float* Wk = (const float*)d_in[3];
    const float* bk = (const float*)d_in[4];
    const float* Wv = (const float*)d_in[5];
    const float* bv = (const float*)d_in[6];
    const float* Wp = (const float*)d_in[7];
    const float* bp = (const float*)d_in[8];
    float* out = (float*)d_out;

    const size_t NN = 16777216;            // 4096*4096 elements
    const int n8 = (int)(NN / 8);
    dim3 cgrid((n8 + 255) / 256), cblk(256);
    dim3 ggrid(1024), gblk(256);

    if (ws_size >= NN * 2 * 8) {
        // merged-cvt path: all 5 converts in one launch (needs 256 MB ws)
        uint16_t* xb  = (uint16_t*)d_ws;   // later reused as Y
        uint16_t* wqb = xb  + NN;
        uint16_t* wkb = wqb + NN;
        uint16_t* wvb = wkb + NN;
        uint16_t* wpb = wvb + NN;
        uint16_t* Qb  = wpb + NN;
        uint16_t* Kb  = Qb  + NN;
        uint16_t* Vb  = Kb  + NN;
        uint16_t* Yb  = xb;

        cvt5<<<dim3(8192 * 5), cblk, 0, stream>>>(x, Wq, Wk, Wv, Wp,
                                                  xb, wqb, wkb, wvb, wpb);
        gemm128<1><<<ggrid, gblk, 0, stream>>>(xb, wqb, bq, (void*)Qb, 4096, 4096, 4096);
        gemm128<1><<<ggrid, gblk, 0, stream>>>(xb, wkb, bk, (void*)Kb, 4096, 4096, 4096);
        gemm128<1><<<ggrid, gblk, 0, stream>>>(xb, wvb, bv, (void*)Vb, 4096, 4096, 4096);
        attn_kernel<<<dim3(4096), dim3(256), 0, stream>>>(Qb, Kb, Vb, Yb);
        gemm128<0><<<ggrid, gblk, 0, stream>>>(Yb, wpb, bp, (void*)out, 4096, 4096, 4096);
    } else {
        // sequential-wb fallback (160 MB ws)
        uint16_t* xb = (uint16_t*)d_ws;
        uint16_t* wb = xb + NN;
        uint16_t* Qb = wb + NN;
        uint16_t* Kb = Qb + NN;
        uint16_t* Vb = Kb + NN;
        uint16_t* Yb = xb;

        cvt_bf16<<<cgrid, cblk, 0, stream>>>(x, xb, n8);
        cvt_bf16<<<cgrid, cblk, 0, stream>>>(Wq, wb, n8);
        gemm128<1><<<ggrid, gblk, 0, stream>>>(xb, wb, bq, (void*)Qb, 4096, 4096, 4096);
        cvt_bf16<<<cgrid, cblk, 0, stream>>>(Wk, wb, n8);
        gemm128<1><<<ggrid, gblk, 0, stream>>>(xb, wb, bk, (void*)Kb, 4096, 4096, 4096);
        cvt_bf16<<<cgrid, cblk, 0, stream>>>(Wv, wb, n8);
        gemm128<1><<<ggrid, gblk, 0, stream>>>(xb, wb, bv, (void*)Vb, 4096, 4096, 4096);
        attn_kernel<<<dim3(4096), dim3(256), 0, stream>>>(Qb, Kb, Vb, Yb);
        cvt_bf16<<<cgrid, cblk, 0, stream>>>(Wp, wb, n8);
        gemm128<0><<<ggrid, gblk, 0, stream>>>(Yb, wb, bp, (void*)out, 4096, 4096, 4096);
    }
}

// Round 12
// 615.150 us; speedup vs baseline: 1.3271x; 1.3271x over previous
//
#include <hip/hip_runtime.h>
#include <stdint.h>

typedef __bf16   bf16x8  __attribute__((ext_vector_type(8)));
typedef float    f32x4   __attribute__((ext_vector_type(4)));
typedef uint16_t u16x8   __attribute__((ext_vector_type(8)));

using as1_cvp = const __attribute__((address_space(1))) void*;
using as3_vp  = __attribute__((address_space(3))) void*;

__device__ __forceinline__ uint16_t f2bf(float f) {
    uint32_t u = __float_as_uint(f);
    u += 0x7FFF + ((u >> 16) & 1);          // RNE
    return (uint16_t)(u >> 16);
}

__device__ __forceinline__ void gload16(const void* g, void* l) {
    __builtin_amdgcn_global_load_lds((as1_cvp)g, (as3_vp)l, 16, 0, 0);
}

#define MFMA16(a, b, c) __builtin_amdgcn_mfma_f32_16x16x32_bf16((a), (b), (c), 0, 0, 0)

// ---------------------------------------------------------------- f32 -> bf16
__global__ __launch_bounds__(256)
void cvt_bf16(const float* __restrict__ in, uint16_t* __restrict__ out, int n8)
{
    int i = blockIdx.x * 256 + threadIdx.x;
    if (i >= n8) return;
    const float4* p = reinterpret_cast<const float4*>(in) + (size_t)i * 2;
    float4 a = p[0], b = p[1];
    u16x8 o;
    o[0] = f2bf(a.x); o[1] = f2bf(a.y); o[2] = f2bf(a.z); o[3] = f2bf(a.w);
    o[4] = f2bf(b.x); o[5] = f2bf(b.y); o[6] = f2bf(b.z); o[7] = f2bf(b.w);
    reinterpret_cast<u16x8*>(out)[i] = o;
}

// ---- merged 5-matrix convert (one launch, saves ~34us of launch overhead)
__global__ __launch_bounds__(256)
void cvt5(const float* __restrict__ s0, const float* __restrict__ s1,
          const float* __restrict__ s2, const float* __restrict__ s3,
          const float* __restrict__ s4,
          uint16_t* __restrict__ d0, uint16_t* __restrict__ d1,
          uint16_t* __restrict__ d2, uint16_t* __restrict__ d3,
          uint16_t* __restrict__ d4)
{
    const int r = blockIdx.x >> 13;
    const float*  src = (r == 0) ? s0 : (r == 1) ? s1 : (r == 2) ? s2
                       : (r == 3) ? s3 : s4;
    uint16_t*     dst = (r == 0) ? d0 : (r == 1) ? d1 : (r == 2) ? d2
                       : (r == 3) ? d3 : d4;
    const int i = (blockIdx.x & 8191) * 256 + threadIdx.x;
    const float4* p = reinterpret_cast<const float4*>(src) + (size_t)i * 2;
    float4 a = p[0], b = p[1];
    u16x8 o;
    o[0] = f2bf(a.x); o[1] = f2bf(a.y); o[2] = f2bf(a.z); o[3] = f2bf(a.w);
    o[4] = f2bf(b.x); o[5] = f2bf(b.y); o[6] = f2bf(b.z); o[7] = f2bf(b.w);
    reinterpret_cast<u16x8*>(dst)[i] = o;
}

// ---------------------------------------------------------------------------
// 256x256 GEMM — r6/r10 structure (measured best: 127us/4096-col, MfmaUtil
// 48%, 0 bank conflicts), generalized to NB output groups of 4096 columns:
// Bt is [NB*4096 x K] (contiguous weight stack), output group sel = cb>>12
// goes to Cout + sel*outStride with its own bias (256-wide column tiles
// never straddle a 4096 boundary). r11 lesson: 128^2 tiles tripled HBM
// fetch (518MB) and went HBM-bound — 256^2 is the right tile.
// 8 waves (2M x 4N), BK=64 as two K-halves of 32; 64B LDS rows, 16B block
// ^= (row>>1)&3. Pipelined fragments: each phase {stage-issue; ds_reads for
// NEXT phase's frags; MFMA on frags read LAST phase}; raw s_barrier does
// not drain lgkm -> compiler's counted lgkmcnt lets prefetch reads fly
// under the current MFMA cluster. ONE vmcnt(4)/tile at ph3 certifies all
// of tile t+1 (queue: kh0(t+1)[4] from t-1, kh1(t+1)[4], kh0(t+2)[4]).
// Tail t>=NT-2: drain 0. WAR: each stage lands >=1 closing-barrier after
// the last read of its LDS slot.
// ---------------------------------------------------------------------------
template <int OUT_BF16>
__global__ __launch_bounds__(512, 2)
void gemm256(const uint16_t* __restrict__ A, const uint16_t* __restrict__ Bt,
             const float* __restrict__ bias0, const float* __restrict__ bias1,
             const float* __restrict__ bias2, void* __restrict__ Cout,
             size_t outStride, int NB, int K)
{
    __shared__ uint16_t lds[65536];        // [buf][kh] x (A 256x32 | B 256x32)
    const int NT = K >> 6;                 // K-tiles of 64
    const int nbx = NB * 16;               // col-blocks (fast axis)

    int bid = blockIdx.x;
    const int cpx = (nbx * 16) >> 3;       // nwg/8 (nwg % 8 == 0)
    bid = (bid & 7) * cpx + (bid >> 3);    // XCD-aware swizzle (bijective)
    const int bx = bid % nbx, by = bid / nbx;
    const int rb = by * 256, cb = bx * 256;

    const int tid  = threadIdx.x;
    const int w    = tid >> 6;
    const int lane = tid & 63;
    const int g    = lane >> 4;
    const int l16  = lane & 15;
    const int wm   = w >> 2;               // 0..1
    const int wn   = w & 3;                // 0..3
    const int srow = lane >> 2;            // stage: 4 lanes per 64B row
    const int sblk = lane & 3;             // stage: 16B block within row

    f32x4 acc[8][4] = {};

    auto stageA = [&](int buf, int kh, int kbase) {
#pragma unroll
        for (int i = 0; i < 2; ++i) {
            const int row = i * 128 + w * 16 + srow;
            const uint16_t* src = A + (size_t)(rb + row) * K + kbase
                                    + ((sblk ^ ((row >> 1) & 3)) << 3);
            gload16(src, &lds[(buf * 2 + kh) * 16384 + i * 4096 + w * 512]);
        }
    };
    auto stageB = [&](int buf, int kh, int kbase) {
#pragma unroll
        for (int i = 0; i < 2; ++i) {
            const int row = i * 128 + w * 16 + srow;
            const uint16_t* src = Bt + (size_t)(cb + row) * K + kbase
                                     + ((sblk ^ ((row >> 1) & 3)) << 3);
            gload16(src, &lds[(buf * 2 + kh) * 16384 + 8192 + i * 4096 + w * 512]);
        }
    };

    auto readA = [&](int base, int grp, bf16x8* dst) {
#pragma unroll
        for (int mi = 0; mi < 4; ++mi) {
            const int r = wm * 128 + grp * 64 + mi * 16 + l16;
            dst[mi] = *reinterpret_cast<const bf16x8*>(
                &lds[base + r * 32 + ((g ^ ((r >> 1) & 3)) << 3)]);
        }
    };
    auto readB = [&](int base, bf16x8* dst) {
#pragma unroll
        for (int n = 0; n < 4; ++n) {
            const int c = wn * 64 + n * 16 + l16;
            dst[n] = *reinterpret_cast<const bf16x8*>(
                &lds[base + 8192 + c * 32 + ((g ^ ((c >> 1) & 3)) << 3)]);
        }
    };

    auto mfma_grp = [&](int grp, const bf16x8* af, const bf16x8* bf) {
        __builtin_amdgcn_s_setprio(1);
#pragma unroll
        for (int mi = 0; mi < 4; ++mi)
#pragma unroll
            for (int n = 0; n < 4; ++n)
                acc[grp * 4 + mi][n] = MFMA16(af[mi], bf[n], acc[grp * 4 + mi][n]);
        __builtin_amdgcn_s_setprio(0);
    };

    // ---- prologue: t0 kh0, t0 kh1, t1 kh0 (12 loads; vmcnt(4) -> t0 landed)
    stageA(0, 0, 0);  stageB(0, 0, 0);
    stageA(0, 1, 32); stageB(0, 1, 32);
    stageA(1, 0, 64); stageB(1, 0, 64);
    asm volatile("s_waitcnt vmcnt(4)" ::: "memory");
    __builtin_amdgcn_s_barrier();

    for (int t = 0; t < NT; ++t) {
        const int cur = t & 1, nxt = cur ^ 1;
        const int b0 = (cur * 2 + 0) * 16384;
        const int b1 = (cur * 2 + 1) * 16384;
        bf16x8 af0[4], af1[4], af2[4], af3[4], bf0[4], bf1[4];

        // ---- ph0: stage Ak1(t+1); read af0,bf0 (certified by ph3(t-1));
        //      prefetch af1; MFMA kh0-grp0
        if (t + 1 < NT) stageA(nxt, 1, (t + 1) * 64 + 32);
        readA(b0, 0, af0); readB(b0, bf0);
        readA(b0, 1, af1);                 // counted-lgkm: flies under MFMA
        mfma_grp(0, af0, bf0);
        __builtin_amdgcn_sched_barrier(0);
        __builtin_amdgcn_s_barrier();

        // ---- ph1: stage Bk1(t+1); prefetch bf1,af2 (kh1); MFMA kh0-grp1
        if (t + 1 < NT) stageB(nxt, 1, (t + 1) * 64 + 32);
        readB(b1, bf1);
        readA(b1, 0, af2);
        mfma_grp(1, af1, bf0);
        __builtin_amdgcn_sched_barrier(0);
        __builtin_amdgcn_s_barrier();

        // ---- ph2: stage Ak0(t+2); prefetch af3; MFMA kh1-grp0
        if (t + 2 < NT) stageA(cur, 0, (t + 2) * 64);
        readA(b1, 1, af3);
        mfma_grp(0, af2, bf1);
        __builtin_amdgcn_sched_barrier(0);
        __builtin_amdgcn_s_barrier();

        // ---- ph3: stage Bk0(t+2); MFMA kh1-grp1; tile-boundary vmcnt
        if (t + 2 < NT) stageB(cur, 0, (t + 2) * 64);
        mfma_grp(1, af3, bf1);
        __builtin_amdgcn_sched_barrier(0);
        if (t >= NT - 2) asm volatile("s_waitcnt vmcnt(0)" ::: "memory");
        else             asm volatile("s_waitcnt vmcnt(4)" ::: "memory");
        __builtin_amdgcn_s_barrier();
    }

    // ---- epilogue: per-block uniform output group (cb>>12); C row stride 4096
    const int  sel  = cb >> 12;
    const int  colb = cb & 4095;
    const float* bias = (sel == 0) ? bias0 : (sel == 1) ? bias1 : bias2;

    float bv[4];
#pragma unroll
    for (int n = 0; n < 4; ++n) bv[n] = bias[colb + wn * 64 + n * 16 + l16];

#pragma unroll
    for (int m = 0; m < 8; ++m) {
#pragma unroll
        for (int n = 0; n < 4; ++n) {
            const int col = colb + wn * 64 + n * 16 + l16;
#pragma unroll
            for (int r = 0; r < 4; ++r) {
                const int row = rb + wm * 128 + m * 16 + g * 4 + r;
                float v = acc[m][n][r] + bv[n];
                if (OUT_BF16)
                    ((uint16_t*)Cout)[sel * outStride + (size_t)row * 4096 + col] = f2bf(v);
                else
                    ((float*)Cout)[sel * outStride + (size_t)row * 4096 + col] = v;
            }
        }
    }
}

// ------------------------------------------------------------------ attention
// One block per (bb, hh). 4 waves; wave w owns query rows [16w, 16w+16).
// Unscaled softmax(Q K^T) V, output scattered through the reference's
// cat/transpose/view permutation directly into Y (bf16 [4096 x 4096]).
__global__ __launch_bounds__(256)
void attn_kernel(const uint16_t* __restrict__ Q, const uint16_t* __restrict__ Kg,
                 const uint16_t* __restrict__ V, uint16_t* __restrict__ Y)
{
    const int bid = blockIdx.x;
    const int hh  = bid & 63;
    const int bb  = bid >> 6;
    const int tid = threadIdx.x;
    const int w   = tid >> 6, lane = tid & 63, g = lane >> 4, l16 = lane & 15;

    __shared__ uint16_t Vt[64 * 64];   // V transposed, XOR-swizzled (8 KB)
    __shared__ uint16_t Pl[64 * 64];   // P bf16, XOR-swizzled (8 KB)

    // ---- stage V transposed: Vt[l][k] = V[k][l], swizzle elem k ^= (l&7)<<3
    {
        const int k  = tid >> 2;
        const int l0 = (tid & 3) * 16;
        const uint16_t* src = V + (size_t)(bb * 64 + k) * 4096 + hh * 64 + l0;
        u16x8 v0 = *reinterpret_cast<const u16x8*>(src);
        u16x8 v1 = *reinterpret_cast<const u16x8*>(src + 8);
#pragma unroll
        for (int i = 0; i < 8; ++i) {
            int l = l0 + i;
            Vt[l * 64 + (k ^ ((l & 7) << 3))] = v0[i];
        }
#pragma unroll
        for (int i = 0; i < 8; ++i) {
            int l = l0 + 8 + i;
            Vt[l * 64 + (k ^ ((l & 7) << 3))] = v1[i];
        }
    }

    // ---- S = Q K^T (rows 16w..16w+16, all 64 cols), direct-global fragments
    f32x4 sa[4] = {};
    {
        const uint16_t* qrow = Q + (size_t)(bb * 64 + w * 16 + l16) * 4096 + hh * 64 + g * 8;
        bf16x8 a0 = *reinterpret_cast<const bf16x8*>(qrow);
        bf16x8 a1 = *reinterpret_cast<const bf16x8*>(qrow + 32);
#pragma unroll
        for (int n = 0; n < 4; ++n) {
            const uint16_t* krow = Kg + (size_t)(bb * 64 + n * 16 + l16) * 4096 + hh * 64 + g * 8;
            bf16x8 b0 = *reinterpret_cast<const bf16x8*>(krow);
            bf16x8 b1 = *reinterpret_cast<const bf16x8*>(krow + 32);
            sa[n] = MFMA16(a0, b0, sa[n]);
            sa[n] = MFMA16(a1, b1, sa[n]);
        }
    }

    // ---- softmax (no 1/sqrt(hd) scale, faithful). Row q = 16w + 4g + j;
    // its 64 values live as regs n=0..3 across the 16-lane group (l16).
    float p[4][4];
#pragma unroll
    for (int j = 0; j < 4; ++j) {
        float mx = fmaxf(fmaxf(sa[0][j], sa[1][j]), fmaxf(sa[2][j], sa[3][j]));
        mx = fmaxf(mx, __shfl_xor(mx, 1));
        mx = fmaxf(mx, __shfl_xor(mx, 2));
        mx = fmaxf(mx, __shfl_xor(mx, 4));
        mx = fmaxf(mx, __shfl_xor(mx, 8));
        float s = 0.f;
#pragma unroll
        for (int n = 0; n < 4; ++n) { p[n][j] = __expf(sa[n][j] - mx); s += p[n][j]; }
        s += __shfl_xor(s, 1);
        s += __shfl_xor(s, 2);
        s += __shfl_xor(s, 4);
        s += __shfl_xor(s, 8);
        float inv = 1.0f / s;
#pragma unroll
        for (int n = 0; n < 4; ++n) p[n][j] *= inv;
    }

    // ---- P -> LDS in A-operand-friendly layout (swizzled)
#pragma unroll
    for (int j = 0; j < 4; ++j) {
        const int q = w * 16 + g * 4 + j;
#pragma unroll
        for (int n = 0; n < 4; ++n) {
            const int kcol = n * 16 + l16;
            Pl[q * 64 + (kcol ^ ((q & 7) << 3))] = f2bf(p[n][j]);
        }
    }
    __syncthreads();   // Vt (all threads) + Pl ready

    // ---- O = P V
    f32x4 oa[4] = {};
    {
        const int qr = w * 16 + l16;
        bf16x8 a0 = *reinterpret_cast<const bf16x8*>(&Pl[qr * 64 + ((g * 8)      ^ ((qr & 7) << 3))]);
        bf16x8 a1 = *reinterpret_cast<const bf16x8*>(&Pl[qr * 64 + ((32 + g * 8) ^ ((qr & 7) << 3))]);
#pragma unroll
        for (int n = 0; n < 4; ++n) {
            const int vr = n * 16 + l16;
            bf16x8 b0 = *reinterpret_cast<const bf16x8*>(&Vt[vr * 64 + ((g * 8)      ^ ((vr & 7) << 3))]);
            bf16x8 b1 = *reinterpret_cast<const bf16x8*>(&Vt[vr * 64 + ((32 + g * 8) ^ ((vr & 7) << 3))]);
            oa[n] = MFMA16(a0, b0, oa[n]);
            oa[n] = MFMA16(a1, b1, oa[n]);
        }
    }

    // ---- permuted store: Ostd[bb,hh,qq,ll] -> Y[b, s, h*64 + l]
#pragma unroll
    for (int n = 0; n < 4; ++n) {
        const int ll = n * 16 + l16;
#pragma unroll
        for (int r = 0; r < 4; ++r) {
            const int qq = w * 16 + g * 4 + r;
            const int b_ = (bb >> 1) + ((ll >= 32) ? 32 : 0);
            const int s_ = ((bb & 1) << 5) + (qq >> 1);
            const int h_ = ((qq & 1) << 5) + (hh >> 1);
            const int l_ = ((hh & 1) << 5) + (ll & 31);
            Y[(size_t)(b_ * 64 + s_) * 4096 + h_ * 64 + l_] = f2bf(oa[n][r]);
        }
    }
}

// ----------------------------------------------------------------------------
extern "C" void kernel_launch(void* const* d_in, const int* in_sizes, int n_in,
                              void* d_out, int out_size, void* d_ws, size_t ws_size,
                              hipStream_t stream)
{
    (void)in_sizes; (void)n_in; (void)out_size;

    const float* x  = (const float*)d_in[0];
    const float* Wq = (const float*)d_in[1];
    const float* bq = (const float*)d_in[2];
    const float* Wk = (const float*)d_in[3];
    const float* bk = (const float*)d_in[4];
    const float* Wv = (const float*)d_in[5];
    const float* bv = (const float*)d_in[6];
    const float* Wp = (const float*)d_in[7];
    const float* bp = (const float*)d_in[8];
    float* out = (float*)d_out;

    const size_t NN = 16777216;            // 4096*4096 elements
    const int n8 = (int)(NN / 8);
    dim3 cgrid((n8 + 255) / 256), cblk(256);

    if (ws_size >= NN * 2 * 8) {
        // merged path: cvt5 writes Wq/Wk/Wv bf16 CONTIGUOUSLY -> one fused
        // QKV GEMM dispatch over Bt = [Wq;Wk;Wv] (12288 x 4096), outputs to
        // contiguous Qb/Kb/Vb (needs 256 MB ws)
        uint16_t* xb  = (uint16_t*)d_ws;   // later reused as Y
        uint16_t* wqb = xb  + NN;
        uint16_t* wkb = wqb + NN;
        uint16_t* wvb = wkb + NN;
        uint16_t* wpb = wvb + NN;
        uint16_t* Qb  = wpb + NN;
        uint16_t* Kb  = Qb  + NN;
        uint16_t* Vb  = Kb  + NN;
        uint16_t* Yb  = xb;

        cvt5<<<dim3(8192 * 5), cblk, 0, stream>>>(x, Wq, Wk, Wv, Wp,
                                                  xb, wqb, wkb, wvb, wpb);
        gemm256<1><<<dim3(768), dim3(512), 0, stream>>>(
            xb, wqb, bq, bk, bv, (void*)Qb, NN, 3, 4096);
        attn_kernel<<<dim3(4096), dim3(256), 0, stream>>>(Qb, Kb, Vb, Yb);
        gemm256<0><<<dim3(256), dim3(512), 0, stream>>>(
            Yb, wpb, bp, bp, bp, (void*)out, NN, 1, 4096);
    } else {
        // sequential-wb fallback (160 MB ws)
        uint16_t* xb = (uint16_t*)d_ws;
        uint16_t* wb = xb + NN;
        uint16_t* Qb = wb + NN;
        uint16_t* Kb = Qb + NN;
        uint16_t* Vb = Kb + NN;
        uint16_t* Yb = xb;

        cvt_bf16<<<cgrid, cblk, 0, stream>>>(x, xb, n8);
        cvt_bf16<<<cgrid, cblk, 0, stream>>>(Wq, wb, n8);
        gemm256<1><<<dim3(256), dim3(512), 0, stream>>>(
            xb, wb, bq, bq, bq, (void*)Qb, NN, 1, 4096);
        cvt_bf16<<<cgrid, cblk, 0, stream>>>(Wk, wb, n8);
        gemm256<1><<<dim3(256), dim3(512), 0, stream>>>(
            xb, wb, bk, bk, bk, (void*)Kb, NN, 1, 4096);
        cvt_bf16<<<cgrid, cblk, 0, stream>>>(Wv, wb, n8);
        gemm256<1><<<dim3(256), dim3(512), 0, stream>>>(
            xb, wb, bv, bv, bv, (void*)Vb, NN, 1, 4096);
        attn_kernel<<<dim3(4096), dim3(256), 0, stream>>>(Qb, Kb, Vb, Yb);
        cvt_bf16<<<cgrid, cblk, 0, stream>>>(Wp, wb, n8);
        gemm256<0><<<dim3(256), dim3(512), 0, stream>>>(
            Yb, wb, bp, bp, bp, (void*)out, NN, 1, 4096);
    }
}

// Round 13
// 607.621 us; speedup vs baseline: 1.3435x; 1.0124x over previous
//
#include <hip/hip_runtime.h>
#include <stdint.h>

typedef __bf16   bf16x8  __attribute__((ext_vector_type(8)));
typedef float    f32x4   __attribute__((ext_vector_type(4)));
typedef uint16_t u16x8   __attribute__((ext_vector_type(8)));

using as1_cvp = const __attribute__((address_space(1))) void*;
using as3_vp  = __attribute__((address_space(3))) void*;

__device__ __forceinline__ uint16_t f2bf(float f) {
    uint32_t u = __float_as_uint(f);
    u += 0x7FFF + ((u >> 16) & 1);          // RNE
    return (uint16_t)(u >> 16);
}

__device__ __forceinline__ void gload16(const void* g, void* l) {
    __builtin_amdgcn_global_load_lds((as1_cvp)g, (as3_vp)l, 16, 0, 0);
}

#define MFMA16(a, b, c) __builtin_amdgcn_mfma_f32_16x16x32_bf16((a), (b), (c), 0, 0, 0)

// ---------------------------------------------------------------- f32 -> bf16
__global__ __launch_bounds__(256)
void cvt_bf16(const float* __restrict__ in, uint16_t* __restrict__ out, int n8)
{
    int i = blockIdx.x * 256 + threadIdx.x;
    if (i >= n8) return;
    const float4* p = reinterpret_cast<const float4*>(in) + (size_t)i * 2;
    float4 a = p[0], b = p[1];
    u16x8 o;
    o[0] = f2bf(a.x); o[1] = f2bf(a.y); o[2] = f2bf(a.z); o[3] = f2bf(a.w);
    o[4] = f2bf(b.x); o[5] = f2bf(b.y); o[6] = f2bf(b.z); o[7] = f2bf(b.w);
    reinterpret_cast<u16x8*>(out)[i] = o;
}

// ---- merged 5-matrix convert (one launch, saves ~34us of launch overhead)
__global__ __launch_bounds__(256)
void cvt5(const float* __restrict__ s0, const float* __restrict__ s1,
          const float* __restrict__ s2, const float* __restrict__ s3,
          const float* __restrict__ s4,
          uint16_t* __restrict__ d0, uint16_t* __restrict__ d1,
          uint16_t* __restrict__ d2, uint16_t* __restrict__ d3,
          uint16_t* __restrict__ d4)
{
    const int r = blockIdx.x >> 13;
    const float*  src = (r == 0) ? s0 : (r == 1) ? s1 : (r == 2) ? s2
                       : (r == 3) ? s3 : s4;
    uint16_t*     dst = (r == 0) ? d0 : (r == 1) ? d1 : (r == 2) ? d2
                       : (r == 3) ? d3 : d4;
    const int i = (blockIdx.x & 8191) * 256 + threadIdx.x;
    const float4* p = reinterpret_cast<const float4*>(src) + (size_t)i * 2;
    float4 a = p[0], b = p[1];
    u16x8 o;
    o[0] = f2bf(a.x); o[1] = f2bf(a.y); o[2] = f2bf(a.z); o[3] = f2bf(a.w);
    o[4] = f2bf(b.x); o[5] = f2bf(b.y); o[6] = f2bf(b.z); o[7] = f2bf(b.w);
    reinterpret_cast<u16x8*>(dst)[i] = o;
}

// ---------------------------------------------------------------------------
// 256x256 GEMM — r6/r10 pipeline, phases merged 4 -> 2 per K-tile (the
// r4->r6 lever applied again: fewer barrier rendezvous, counted waits).
// C = A*Bt^T + bias, bf16 operands. SEPARATE dispatch per weight (r12
// lesson: fused 12288-col Bt sweeps 96MB/XCD through L2 -> FETCH 3x).
// 8 waves (2M x 4N), BK=64 as two K-halves of 32; 64B LDS rows, 16B block
// ^= (row>>1)&3 (0 conflicts). Per tile:
//  ph0: stage kh1(t+1) A+B; read kh0 frags; MFMA kh0 grp0+grp1; bar.
//  ph1: stage kh0(t+2) A+B; read kh1 frags; MFMA kh1 both; vmcnt; bar.
// WAR: b0 overwritten at t ph1 (= after ph0 bar certifies kh0 consumed);
// b1 overwritten at t+1 ph0 (= after t ph1 bar). vmcnt (in-order) at ph1
// end: queue = kh0(t+1)[4], kh1(t+1)[4], kh0(t+2)[4] -> vmcnt(4) certifies
// ALL of tile t+1. Prologue vmcnt(4) certifies t0. Tail t>=NT-2: drain 0.
// Frags consumed in-phase -> peak VGPR stays ~112 (2 waves/SIMD safe).
// ---------------------------------------------------------------------------
template <int OUT_BF16>
__global__ __launch_bounds__(512, 2)
void gemm256(const uint16_t* __restrict__ A, const uint16_t* __restrict__ Bt,
             const float* __restrict__ bias, void* __restrict__ Cout,
             int M, int N, int K)
{
    __shared__ uint16_t lds[65536];        // [buf][kh] x (A 256x32 | B 256x32)
    const int NT = K >> 6;                 // K-tiles of 64

    int bid = blockIdx.x;
    bid = (bid & 7) * 32 + (bid >> 3);     // XCD-aware swizzle (nwg=256, %8==0)
    const int bx = bid & 15, by = bid >> 4;
    const int rb = by * 256, cb = bx * 256;

    const int tid  = threadIdx.x;
    const int w    = tid >> 6;
    const int lane = tid & 63;
    const int g    = lane >> 4;
    const int l16  = lane & 15;
    const int wm   = w >> 2;               // 0..1
    const int wn   = w & 3;                // 0..3
    const int srow = lane >> 2;            // stage: 4 lanes per 64B row
    const int sblk = lane & 3;             // stage: 16B block within row

    f32x4 acc[8][4] = {};

    auto stageA = [&](int buf, int kh, int kbase) {
#pragma unroll
        for (int i = 0; i < 2; ++i) {
            const int row = i * 128 + w * 16 + srow;
            const uint16_t* src = A + (size_t)(rb + row) * K + kbase
                                    + ((sblk ^ ((row >> 1) & 3)) << 3);
            gload16(src, &lds[(buf * 2 + kh) * 16384 + i * 4096 + w * 512]);
        }
    };
    auto stageB = [&](int buf, int kh, int kbase) {
#pragma unroll
        for (int i = 0; i < 2; ++i) {
            const int row = i * 128 + w * 16 + srow;
            const uint16_t* src = Bt + (size_t)(cb + row) * K + kbase
                                     + ((sblk ^ ((row >> 1) & 3)) << 3);
            gload16(src, &lds[(buf * 2 + kh) * 16384 + 8192 + i * 4096 + w * 512]);
        }
    };

    auto readA = [&](int base, int grp, bf16x8* dst) {
#pragma unroll
        for (int mi = 0; mi < 4; ++mi) {
            const int r = wm * 128 + grp * 64 + mi * 16 + l16;
            dst[mi] = *reinterpret_cast<const bf16x8*>(
                &lds[base + r * 32 + ((g ^ ((r >> 1) & 3)) << 3)]);
        }
    };
    auto readB = [&](int base, bf16x8* dst) {
#pragma unroll
        for (int n = 0; n < 4; ++n) {
            const int c = wn * 64 + n * 16 + l16;
            dst[n] = *reinterpret_cast<const bf16x8*>(
                &lds[base + 8192 + c * 32 + ((g ^ ((c >> 1) & 3)) << 3)]);
        }
    };

    auto mfma_grp = [&](int grp, const bf16x8* af, const bf16x8* bf) {
        __builtin_amdgcn_s_setprio(1);
#pragma unroll
        for (int mi = 0; mi < 4; ++mi)
#pragma unroll
            for (int n = 0; n < 4; ++n)
                acc[grp * 4 + mi][n] = MFMA16(af[mi], bf[n], acc[grp * 4 + mi][n]);
        __builtin_amdgcn_s_setprio(0);
    };

    // ---- prologue: t0 kh0, t0 kh1, t1 kh0 (12 loads; vmcnt(4) -> t0 landed)
    stageA(0, 0, 0);  stageB(0, 0, 0);
    stageA(0, 1, 32); stageB(0, 1, 32);
    stageA(1, 0, 64); stageB(1, 0, 64);
    asm volatile("s_waitcnt vmcnt(4)" ::: "memory");
    __builtin_amdgcn_s_barrier();

    for (int t = 0; t < NT; ++t) {
        const int cur = t & 1, nxt = cur ^ 1;
        const int b0 = (cur * 2 + 0) * 16384;
        const int b1 = (cur * 2 + 1) * 16384;
        bf16x8 afa[4], afb[4], bfr[4];

        // ---- ph0: stage kh1(t+1); read kh0 frags; MFMA kh0 (both grps)
        if (t + 1 < NT) { stageA(nxt, 1, (t + 1) * 64 + 32);
                          stageB(nxt, 1, (t + 1) * 64 + 32); }
        readA(b0, 0, afa); readB(b0, bfr);
        readA(b0, 1, afb);
        mfma_grp(0, afa, bfr);
        mfma_grp(1, afb, bfr);
        __builtin_amdgcn_sched_barrier(0);
        __builtin_amdgcn_s_barrier();

        // ---- ph1: stage kh0(t+2); read kh1 frags; MFMA kh1; tile vmcnt
        if (t + 2 < NT) { stageA(cur, 0, (t + 2) * 64);
                          stageB(cur, 0, (t + 2) * 64); }
        readA(b1, 0, afa); readB(b1, bfr);
        readA(b1, 1, afb);
        mfma_grp(0, afa, bfr);
        mfma_grp(1, afb, bfr);
        __builtin_amdgcn_sched_barrier(0);
        if (t >= NT - 2) asm volatile("s_waitcnt vmcnt(0)" ::: "memory");
        else             asm volatile("s_waitcnt vmcnt(4)" ::: "memory");
        __builtin_amdgcn_s_barrier();
    }

    // ---- epilogue (16x16 C/D layout: col = l16, row = 4g + r)
    float bv[4];
#pragma unroll
    for (int n = 0; n < 4; ++n) bv[n] = bias[cb + wn * 64 + n * 16 + l16];

#pragma unroll
    for (int m = 0; m < 8; ++m) {
#pragma unroll
        for (int n = 0; n < 4; ++n) {
            const int col = cb + wn * 64 + n * 16 + l16;
#pragma unroll
            for (int r = 0; r < 4; ++r) {
                const int row = rb + wm * 128 + m * 16 + g * 4 + r;
                float v = acc[m][n][r] + bv[n];
                if (OUT_BF16)
                    ((uint16_t*)Cout)[(size_t)row * N + col] = f2bf(v);
                else
                    ((float*)Cout)[(size_t)row * N + col] = v;
            }
        }
    }
}

// ------------------------------------------------------------------ attention
// One block per (bb, hh). 4 waves; wave w owns query rows [16w, 16w+16).
// Unscaled softmax(Q K^T) V, output scattered through the reference's
// cat/transpose/view permutation directly into Y (bf16 [4096 x 4096]).
__global__ __launch_bounds__(256)
void attn_kernel(const uint16_t* __restrict__ Q, const uint16_t* __restrict__ Kg,
                 const uint16_t* __restrict__ V, uint16_t* __restrict__ Y)
{
    const int bid = blockIdx.x;
    const int hh  = bid & 63;
    const int bb  = bid >> 6;
    const int tid = threadIdx.x;
    const int w   = tid >> 6, lane = tid & 63, g = lane >> 4, l16 = lane & 15;

    __shared__ uint16_t Vt[64 * 64];   // V transposed, XOR-swizzled (8 KB)
    __shared__ uint16_t Pl[64 * 64];   // P bf16, XOR-swizzled (8 KB)

    // ---- stage V transposed: Vt[l][k] = V[k][l], swizzle elem k ^= (l&7)<<3
    {
        const int k  = tid >> 2;
        const int l0 = (tid & 3) * 16;
        const uint16_t* src = V + (size_t)(bb * 64 + k) * 4096 + hh * 64 + l0;
        u16x8 v0 = *reinterpret_cast<const u16x8*>(src);
        u16x8 v1 = *reinterpret_cast<const u16x8*>(src + 8);
#pragma unroll
        for (int i = 0; i < 8; ++i) {
            int l = l0 + i;
            Vt[l * 64 + (k ^ ((l & 7) << 3))] = v0[i];
        }
#pragma unroll
        for (int i = 0; i < 8; ++i) {
            int l = l0 + 8 + i;
            Vt[l * 64 + (k ^ ((l & 7) << 3))] = v1[i];
        }
    }

    // ---- S = Q K^T (rows 16w..16w+16, all 64 cols), direct-global fragments
    f32x4 sa[4] = {};
    {
        const uint16_t* qrow = Q + (size_t)(bb * 64 + w * 16 + l16) * 4096 + hh * 64 + g * 8;
        bf16x8 a0 = *reinterpret_cast<const bf16x8*>(qrow);
        bf16x8 a1 = *reinterpret_cast<const bf16x8*>(qrow + 32);
#pragma unroll
        for (int n = 0; n < 4; ++n) {
            const uint16_t* krow = Kg + (size_t)(bb * 64 + n * 16 + l16) * 4096 + hh * 64 + g * 8;
            bf16x8 b0 = *reinterpret_cast<const bf16x8*>(krow);
            bf16x8 b1 = *reinterpret_cast<const bf16x8*>(krow + 32);
            sa[n] = MFMA16(a0, b0, sa[n]);
            sa[n] = MFMA16(a1, b1, sa[n]);
        }
    }

    // ---- softmax (no 1/sqrt(hd) scale, faithful). Row q = 16w + 4g + j;
    // its 64 values live as regs n=0..3 across the 16-lane group (l16).
    float p[4][4];
#pragma unroll
    for (int j = 0; j < 4; ++j) {
        float mx = fmaxf(fmaxf(sa[0][j], sa[1][j]), fmaxf(sa[2][j], sa[3][j]));
        mx = fmaxf(mx, __shfl_xor(mx, 1));
        mx = fmaxf(mx, __shfl_xor(mx, 2));
        mx = fmaxf(mx, __shfl_xor(mx, 4));
        mx = fmaxf(mx, __shfl_xor(mx, 8));
        float s = 0.f;
#pragma unroll
        for (int n = 0; n < 4; ++n) { p[n][j] = __expf(sa[n][j] - mx); s += p[n][j]; }
        s += __shfl_xor(s, 1);
        s += __shfl_xor(s, 2);
        s += __shfl_xor(s, 4);
        s += __shfl_xor(s, 8);
        float inv = 1.0f / s;
#pragma unroll
        for (int n = 0; n < 4; ++n) p[n][j] *= inv;
    }

    // ---- P -> LDS in A-operand-friendly layout (swizzled)
#pragma unroll
    for (int j = 0; j < 4; ++j) {
        const int q = w * 16 + g * 4 + j;
#pragma unroll
        for (int n = 0; n < 4; ++n) {
            const int kcol = n * 16 + l16;
            Pl[q * 64 + (kcol ^ ((q & 7) << 3))] = f2bf(p[n][j]);
        }
    }
    __syncthreads();   // Vt (all threads) + Pl ready

    // ---- O = P V
    f32x4 oa[4] = {};
    {
        const int qr = w * 16 + l16;
        bf16x8 a0 = *reinterpret_cast<const bf16x8*>(&Pl[qr * 64 + ((g * 8)      ^ ((qr & 7) << 3))]);
        bf16x8 a1 = *reinterpret_cast<const bf16x8*>(&Pl[qr * 64 + ((32 + g * 8) ^ ((qr & 7) << 3))]);
#pragma unroll
        for (int n = 0; n < 4; ++n) {
            const int vr = n * 16 + l16;
            bf16x8 b0 = *reinterpret_cast<const bf16x8*>(&Vt[vr * 64 + ((g * 8)      ^ ((vr & 7) << 3))]);
            bf16x8 b1 = *reinterpret_cast<const bf16x8*>(&Vt[vr * 64 + ((32 + g * 8) ^ ((vr & 7) << 3))]);
            oa[n] = MFMA16(a0, b0, oa[n]);
            oa[n] = MFMA16(a1, b1, oa[n]);
        }
    }

    // ---- permuted store: Ostd[bb,hh,qq,ll] -> Y[b, s, h*64 + l]
#pragma unroll
    for (int n = 0; n < 4; ++n) {
        const int ll = n * 16 + l16;
#pragma unroll
        for (int r = 0; r < 4; ++r) {
            const int qq = w * 16 + g * 4 + r;
            const int b_ = (bb >> 1) + ((ll >= 32) ? 32 : 0);
            const int s_ = ((bb & 1) << 5) + (qq >> 1);
            const int h_ = ((qq & 1) << 5) + (hh >> 1);
            const int l_ = ((hh & 1) << 5) + (ll & 31);
            Y[(size_t)(b_ * 64 + s_) * 4096 + h_ * 64 + l_] = f2bf(oa[n][r]);
        }
    }
}

// ----------------------------------------------------------------------------
extern "C" void kernel_launch(void* const* d_in, const int* in_sizes, int n_in,
                              void* d_out, int out_size, void* d_ws, size_t ws_size,
                              hipStream_t stream)
{
    (void)in_sizes; (void)n_in; (void)out_size;

    const float* x  = (const float*)d_in[0];
    const float* Wq = (const float*)d_in[1];
    const float* bq = (const float*)d_in[2];
    const float* Wk = (const float*)d_in[3];
    const float* bk = (const float*)d_in[4];
    const float* Wv = (const float*)d_in[5];
    const float* bv = (const float*)d_in[6];
    const float* Wp = (const float*)d_in[7];
    const float* bp = (const float*)d_in[8];
    float* out = (float*)d_out;

    const size_t NN = 16777216;            // 4096*4096 elements
    const int n8 = (int)(NN / 8);
    dim3 cgrid((n8 + 255) / 256), cblk(256);
    dim3 ggrid(256), gblk(512);

    if (ws_size >= NN * 2 * 8) {
        // merged-cvt path: all 5 converts in one launch (needs 256 MB ws);
        // SEPARATE QKV GEMM dispatches (r12: fusion triples FETCH, no gain)
        uint16_t* xb  = (uint16_t*)d_ws;   // later reused as Y
        uint16_t* wqb = xb  + NN;
        uint16_t* wkb = wqb + NN;
        uint16_t* wvb = wkb + NN;
        uint16_t* wpb = wvb + NN;
        uint16_t* Qb  = wpb + NN;
        uint16_t* Kb  = Qb  + NN;
        uint16_t* Vb  = Kb  + NN;
        uint16_t* Yb  = xb;

        cvt5<<<dim3(8192 * 5), cblk, 0, stream>>>(x, Wq, Wk, Wv, Wp,
                                                  xb, wqb, wkb, wvb, wpb);
        gemm256<1><<<ggrid, gblk, 0, stream>>>(xb, wqb, bq, (void*)Qb, 4096, 4096, 4096);
        gemm256<1><<<ggrid, gblk, 0, stream>>>(xb, wkb, bk, (void*)Kb, 4096, 4096, 4096);
        gemm256<1><<<ggrid, gblk, 0, stream>>>(xb, wvb, bv, (void*)Vb, 4096, 4096, 4096);
        attn_kernel<<<dim3(4096), dim3(256), 0, stream>>>(Qb, Kb, Vb, Yb);
        gemm256<0><<<ggrid, gblk, 0, stream>>>(Yb, wpb, bp, (void*)out, 4096, 4096, 4096);
    } else {
        // sequential-wb fallback (160 MB ws)
        uint16_t* xb = (uint16_t*)d_ws;
        uint16_t* wb = xb + NN;
        uint16_t* Qb = wb + NN;
        uint16_t* Kb = Qb + NN;
        uint16_t* Vb = Kb + NN;
        uint16_t* Yb = xb;

        cvt_bf16<<<cgrid, cblk, 0, stream>>>(x, xb, n8);
        cvt_bf16<<<cgrid, cblk, 0, stream>>>(Wq, wb, n8);
        gemm256<1><<<ggrid, gblk, 0, stream>>>(xb, wb, bq, (void*)Qb, 4096, 4096, 4096);
        cvt_bf16<<<cgrid, cblk, 0, stream>>>(Wk, wb, n8);
        gemm256<1><<<ggrid, gblk, 0, stream>>>(xb, wb, bk, (void*)Kb, 4096, 4096, 4096);
        cvt_bf16<<<cgrid, cblk, 0, stream>>>(Wv, wb, n8);
        gemm256<1><<<ggrid, gblk, 0, stream>>>(xb, wb, bv, (void*)Vb, 4096, 4096, 4096);
        attn_kernel<<<dim3(4096), dim3(256), 0, stream>>>(Qb, Kb, Vb, Yb);
        cvt_bf16<<<cgrid, cblk, 0, stream>>>(Wp, wb, n8);
        gemm256<0><<<ggrid, gblk, 0, stream>>>(Yb, wb, bp, (void*)out, 4096, 4096, 4096);
    }
}

// Round 14
// 599.806 us; speedup vs baseline: 1.3610x; 1.0130x over previous
//
#include <hip/hip_runtime.h>
#include <stdint.h>

typedef __bf16   bf16x8  __attribute__((ext_vector_type(8)));
typedef float    f32x4   __attribute__((ext_vector_type(4)));
typedef uint16_t u16x8   __attribute__((ext_vector_type(8)));

using as1_cvp = const __attribute__((address_space(1))) void*;
using as3_vp  = __attribute__((address_space(3))) void*;

__device__ __forceinline__ uint16_t f2bf(float f) {
    uint32_t u = __float_as_uint(f);
    u += 0x7FFF + ((u >> 16) & 1);          // RNE
    return (uint16_t)(u >> 16);
}

__device__ __forceinline__ void gload16(const void* g, void* l) {
    __builtin_amdgcn_global_load_lds((as1_cvp)g, (as3_vp)l, 16, 0, 0);
}

#define MFMA16(a, b, c) __builtin_amdgcn_mfma_f32_16x16x32_bf16((a), (b), (c), 0, 0, 0)

// ---------------------------------------------------------------- f32 -> bf16
__global__ __launch_bounds__(256)
void cvt_bf16(const float* __restrict__ in, uint16_t* __restrict__ out, int n8)
{
    int i = blockIdx.x * 256 + threadIdx.x;
    if (i >= n8) return;
    const float4* p = reinterpret_cast<const float4*>(in) + (size_t)i * 2;
    float4 a = p[0], b = p[1];
    u16x8 o;
    o[0] = f2bf(a.x); o[1] = f2bf(a.y); o[2] = f2bf(a.z); o[3] = f2bf(a.w);
    o[4] = f2bf(b.x); o[5] = f2bf(b.y); o[6] = f2bf(b.z); o[7] = f2bf(b.w);
    reinterpret_cast<u16x8*>(out)[i] = o;
}

// ---- merged 5-matrix convert (one launch, saves ~34us of launch overhead)
__global__ __launch_bounds__(256)
void cvt5(const float* __restrict__ s0, const float* __restrict__ s1,
          const float* __restrict__ s2, const float* __restrict__ s3,
          const float* __restrict__ s4,
          uint16_t* __restrict__ d0, uint16_t* __restrict__ d1,
          uint16_t* __restrict__ d2, uint16_t* __restrict__ d3,
          uint16_t* __restrict__ d4)
{
    const int r = blockIdx.x >> 13;
    const float*  src = (r == 0) ? s0 : (r == 1) ? s1 : (r == 2) ? s2
                       : (r == 3) ? s3 : s4;
    uint16_t*     dst = (r == 0) ? d0 : (r == 1) ? d1 : (r == 2) ? d2
                       : (r == 3) ? d3 : d4;
    const int i = (blockIdx.x & 8191) * 256 + threadIdx.x;
    const float4* p = reinterpret_cast<const float4*>(src) + (size_t)i * 2;
    float4 a = p[0], b = p[1];
    u16x8 o;
    o[0] = f2bf(a.x); o[1] = f2bf(a.y); o[2] = f2bf(a.z); o[3] = f2bf(a.w);
    o[4] = f2bf(b.x); o[5] = f2bf(b.y); o[6] = f2bf(b.z); o[7] = f2bf(b.w);
    reinterpret_cast<u16x8*>(dst)[i] = o;
}

// ---------------------------------------------------------------------------
// 256x256 GEMM — measured-best configuration (r10: 127us, MfmaUtil 48%,
// 0 bank conflicts, 1082 TF). C = A*Bt^T + bias, bf16 operands.
// Explored axes, all optima = this config: tile 256^2 (128^2 HBM-bound,
// r11); MFMA 16x16x32 (32x32 regressed, r5); gload_lds staging (f32-reg
// thrashes L2, r7); 4 phases/tile (8-lockstep 137, 2-merged 132, r9/r13);
// separate QKV dispatches (fusion 3x FETCH, r12).
// 8 waves (2M x 4N), BK=64 as two K-halves of 32; 64B LDS rows, 16B block
// ^= (row>>1)&3. Pipelined fragments: each phase {stage-issue; ds_reads for
// NEXT phase's frags; MFMA on frags read LAST phase}; raw s_barrier does
// not drain lgkm -> compiler's counted lgkmcnt lets prefetch reads fly
// under the current MFMA cluster. ONE vmcnt(4)/tile at ph3 certifies all
// of tile t+1 (in-order queue: kh0(t+1)[4 from t-1], kh1(t+1)[4], kh0(t+2)
// [4] -> wait-to-4 completes through kh1(t+1)). Tail t>=NT-2: drain 0.
// WAR: each stage lands >=1 closing-barrier after the last read of its
// LDS slot.
// ---------------------------------------------------------------------------
template <int OUT_BF16>
__global__ __launch_bounds__(512, 2)
void gemm256(const uint16_t* __restrict__ A, const uint16_t* __restrict__ Bt,
             const float* __restrict__ bias, void* __restrict__ Cout,
             int M, int N, int K)
{
    __shared__ uint16_t lds[65536];        // [buf][kh] x (A 256x32 | B 256x32)
    const int NT = K >> 6;                 // K-tiles of 64

    int bid = blockIdx.x;
    bid = (bid & 7) * 32 + (bid >> 3);     // XCD-aware swizzle (nwg=256, %8==0)
    const int bx = bid & 15, by = bid >> 4;
    const int rb = by * 256, cb = bx * 256;

    const int tid  = threadIdx.x;
    const int w    = tid >> 6;
    const int lane = tid & 63;
    const int g    = lane >> 4;
    const int l16  = lane & 15;
    const int wm   = w >> 2;               // 0..1
    const int wn   = w & 3;                // 0..3
    const int srow = lane >> 2;            // stage: 4 lanes per 64B row
    const int sblk = lane & 3;             // stage: 16B block within row

    f32x4 acc[8][4] = {};

    auto stageA = [&](int buf, int kh, int kbase) {
#pragma unroll
        for (int i = 0; i < 2; ++i) {
            const int row = i * 128 + w * 16 + srow;
            const uint16_t* src = A + (size_t)(rb + row) * K + kbase
                                    + ((sblk ^ ((row >> 1) & 3)) << 3);
            gload16(src, &lds[(buf * 2 + kh) * 16384 + i * 4096 + w * 512]);
        }
    };
    auto stageB = [&](int buf, int kh, int kbase) {
#pragma unroll
        for (int i = 0; i < 2; ++i) {
            const int row = i * 128 + w * 16 + srow;
            const uint16_t* src = Bt + (size_t)(cb + row) * K + kbase
                                     + ((sblk ^ ((row >> 1) & 3)) << 3);
            gload16(src, &lds[(buf * 2 + kh) * 16384 + 8192 + i * 4096 + w * 512]);
        }
    };

    auto readA = [&](int base, int grp, bf16x8* dst) {
#pragma unroll
        for (int mi = 0; mi < 4; ++mi) {
            const int r = wm * 128 + grp * 64 + mi * 16 + l16;
            dst[mi] = *reinterpret_cast<const bf16x8*>(
                &lds[base + r * 32 + ((g ^ ((r >> 1) & 3)) << 3)]);
        }
    };
    auto readB = [&](int base, bf16x8* dst) {
#pragma unroll
        for (int n = 0; n < 4; ++n) {
            const int c = wn * 64 + n * 16 + l16;
            dst[n] = *reinterpret_cast<const bf16x8*>(
                &lds[base + 8192 + c * 32 + ((g ^ ((c >> 1) & 3)) << 3)]);
        }
    };

    auto mfma_grp = [&](int grp, const bf16x8* af, const bf16x8* bf) {
        __builtin_amdgcn_s_setprio(1);
#pragma unroll
        for (int mi = 0; mi < 4; ++mi)
#pragma unroll
            for (int n = 0; n < 4; ++n)
                acc[grp * 4 + mi][n] = MFMA16(af[mi], bf[n], acc[grp * 4 + mi][n]);
        __builtin_amdgcn_s_setprio(0);
    };

    // ---- prologue: t0 kh0, t0 kh1, t1 kh0 (12 loads; vmcnt(4) -> t0 landed)
    stageA(0, 0, 0);  stageB(0, 0, 0);
    stageA(0, 1, 32); stageB(0, 1, 32);
    stageA(1, 0, 64); stageB(1, 0, 64);
    asm volatile("s_waitcnt vmcnt(4)" ::: "memory");
    __builtin_amdgcn_s_barrier();

    for (int t = 0; t < NT; ++t) {
        const int cur = t & 1, nxt = cur ^ 1;
        const int b0 = (cur * 2 + 0) * 16384;
        const int b1 = (cur * 2 + 1) * 16384;
        bf16x8 af0[4], af1[4], af2[4], af3[4], bf0[4], bf1[4];

        // ---- ph0: stage Ak1(t+1); read af0,bf0 (certified by ph3(t-1));
        //      prefetch af1; MFMA kh0-grp0
        if (t + 1 < NT) stageA(nxt, 1, (t + 1) * 64 + 32);
        readA(b0, 0, af0); readB(b0, bf0);
        readA(b0, 1, af1);                 // counted-lgkm: flies under MFMA
        mfma_grp(0, af0, bf0);
        __builtin_amdgcn_sched_barrier(0);
        __builtin_amdgcn_s_barrier();

        // ---- ph1: stage Bk1(t+1); prefetch bf1,af2 (kh1); MFMA kh0-grp1
        if (t + 1 < NT) stageB(nxt, 1, (t + 1) * 64 + 32);
        readB(b1, bf1);
        readA(b1, 0, af2);
        mfma_grp(1, af1, bf0);
        __builtin_amdgcn_sched_barrier(0);
        __builtin_amdgcn_s_barrier();

        // ---- ph2: stage Ak0(t+2); prefetch af3; MFMA kh1-grp0
        if (t + 2 < NT) stageA(cur, 0, (t + 2) * 64);
        readA(b1, 1, af3);
        mfma_grp(0, af2, bf1);
        __builtin_amdgcn_sched_barrier(0);
        __builtin_amdgcn_s_barrier();

        // ---- ph3: stage Bk0(t+2); MFMA kh1-grp1; tile-boundary vmcnt
        if (t + 2 < NT) stageB(cur, 0, (t + 2) * 64);
        mfma_grp(1, af3, bf1);
        __builtin_amdgcn_sched_barrier(0);
        if (t >= NT - 2) asm volatile("s_waitcnt vmcnt(0)" ::: "memory");
        else             asm volatile("s_waitcnt vmcnt(4)" ::: "memory");
        __builtin_amdgcn_s_barrier();
    }

    // ---- epilogue (16x16 C/D layout: col = l16, row = 4g + r)
    float bv[4];
#pragma unroll
    for (int n = 0; n < 4; ++n) bv[n] = bias[cb + wn * 64 + n * 16 + l16];

#pragma unroll
    for (int m = 0; m < 8; ++m) {
#pragma unroll
        for (int n = 0; n < 4; ++n) {
            const int col = cb + wn * 64 + n * 16 + l16;
#pragma unroll
            for (int r = 0; r < 4; ++r) {
                const int row = rb + wm * 128 + m * 16 + g * 4 + r;
                float v = acc[m][n][r] + bv[n];
                if (OUT_BF16)
                    ((uint16_t*)Cout)[(size_t)row * N + col] = f2bf(v);
                else
                    ((float*)Cout)[(size_t)row * N + col] = v;
            }
        }
    }
}

// ------------------------------------------------------------------ attention
// One block per (bb, hh). 4 waves; wave w owns query rows [16w, 16w+16).
// Unscaled softmax(Q K^T) V, output scattered through the reference's
// cat/transpose/view permutation directly into Y (bf16 [4096 x 4096]).
__global__ __launch_bounds__(256)
void attn_kernel(const uint16_t* __restrict__ Q, const uint16_t* __restrict__ Kg,
                 const uint16_t* __restrict__ V, uint16_t* __restrict__ Y)
{
    const int bid = blockIdx.x;
    const int hh  = bid & 63;
    const int bb  = bid >> 6;
    const int tid = threadIdx.x;
    const int w   = tid >> 6, lane = tid & 63, g = lane >> 4, l16 = lane & 15;

    __shared__ uint16_t Vt[64 * 64];   // V transposed, XOR-swizzled (8 KB)
    __shared__ uint16_t Pl[64 * 64];   // P bf16, XOR-swizzled (8 KB)

    // ---- stage V transposed: Vt[l][k] = V[k][l], swizzle elem k ^= (l&7)<<3
    {
        const int k  = tid >> 2;
        const int l0 = (tid & 3) * 16;
        const uint16_t* src = V + (size_t)(bb * 64 + k) * 4096 + hh * 64 + l0;
        u16x8 v0 = *reinterpret_cast<const u16x8*>(src);
        u16x8 v1 = *reinterpret_cast<const u16x8*>(src + 8);
#pragma unroll
        for (int i = 0; i < 8; ++i) {
            int l = l0 + i;
            Vt[l * 64 + (k ^ ((l & 7) << 3))] = v0[i];
        }
#pragma unroll
        for (int i = 0; i < 8; ++i) {
            int l = l0 + 8 + i;
            Vt[l * 64 + (k ^ ((l & 7) << 3))] = v1[i];
        }
    }

    // ---- S = Q K^T (rows 16w..16w+16, all 64 cols), direct-global fragments
    f32x4 sa[4] = {};
    {
        const uint16_t* qrow = Q + (size_t)(bb * 64 + w * 16 + l16) * 4096 + hh * 64 + g * 8;
        bf16x8 a0 = *reinterpret_cast<const bf16x8*>(qrow);
        bf16x8 a1 = *reinterpret_cast<const bf16x8*>(qrow + 32);
#pragma unroll
        for (int n = 0; n < 4; ++n) {
            const uint16_t* krow = Kg + (size_t)(bb * 64 + n * 16 + l16) * 4096 + hh * 64 + g * 8;
            bf16x8 b0 = *reinterpret_cast<const bf16x8*>(krow);
            bf16x8 b1 = *reinterpret_cast<const bf16x8*>(krow + 32);
            sa[n] = MFMA16(a0, b0, sa[n]);
            sa[n] = MFMA16(a1, b1, sa[n]);
        }
    }

    // ---- softmax (no 1/sqrt(hd) scale, faithful). Row q = 16w + 4g + j;
    // its 64 values live as regs n=0..3 across the 16-lane group (l16).
    float p[4][4];
#pragma unroll
    for (int j = 0; j < 4; ++j) {
        float mx = fmaxf(fmaxf(sa[0][j], sa[1][j]), fmaxf(sa[2][j], sa[3][j]));
        mx = fmaxf(mx, __shfl_xor(mx, 1));
        mx = fmaxf(mx, __shfl_xor(mx, 2));
        mx = fmaxf(mx, __shfl_xor(mx, 4));
        mx = fmaxf(mx, __shfl_xor(mx, 8));
        float s = 0.f;
#pragma unroll
        for (int n = 0; n < 4; ++n) { p[n][j] = __expf(sa[n][j] - mx); s += p[n][j]; }
        s += __shfl_xor(s, 1);
        s += __shfl_xor(s, 2);
        s += __shfl_xor(s, 4);
        s += __shfl_xor(s, 8);
        float inv = 1.0f / s;
#pragma unroll
        for (int n = 0; n < 4; ++n) p[n][j] *= inv;
    }

    // ---- P -> LDS in A-operand-friendly layout (swizzled)
#pragma unroll
    for (int j = 0; j < 4; ++j) {
        const int q = w * 16 + g * 4 + j;
#pragma unroll
        for (int n = 0; n < 4; ++n) {
            const int kcol = n * 16 + l16;
            Pl[q * 64 + (kcol ^ ((q & 7) << 3))] = f2bf(p[n][j]);
        }
    }
    __syncthreads();   // Vt (all threads) + Pl ready

    // ---- O = P V
    f32x4 oa[4] = {};
    {
        const int qr = w * 16 + l16;
        bf16x8 a0 = *reinterpret_cast<const bf16x8*>(&Pl[qr * 64 + ((g * 8)      ^ ((qr & 7) << 3))]);
        bf16x8 a1 = *reinterpret_cast<const bf16x8*>(&Pl[qr * 64 + ((32 + g * 8) ^ ((qr & 7) << 3))]);
#pragma unroll
        for (int n = 0; n < 4; ++n) {
            const int vr = n * 16 + l16;
            bf16x8 b0 = *reinterpret_cast<const bf16x8*>(&Vt[vr * 64 + ((g * 8)      ^ ((vr & 7) << 3))]);
            bf16x8 b1 = *reinterpret_cast<const bf16x8*>(&Vt[vr * 64 + ((32 + g * 8) ^ ((vr & 7) << 3))]);
            oa[n] = MFMA16(a0, b0, oa[n]);
            oa[n] = MFMA16(a1, b1, oa[n]);
        }
    }

    // ---- permuted store: Ostd[bb,hh,qq,ll] -> Y[b, s, h*64 + l]
#pragma unroll
    for (int n = 0; n < 4; ++n) {
        const int ll = n * 16 + l16;
#pragma unroll
        for (int r = 0; r < 4; ++r) {
            const int qq = w * 16 + g * 4 + r;
            const int b_ = (bb >> 1) + ((ll >= 32) ? 32 : 0);
            const int s_ = ((bb & 1) << 5) + (qq >> 1);
            const int h_ = ((qq & 1) << 5) + (hh >> 1);
            const int l_ = ((hh & 1) << 5) + (ll & 31);
            Y[(size_t)(b_ * 64 + s_) * 4096 + h_ * 64 + l_] = f2bf(oa[n][r]);
        }
    }
}

// ----------------------------------------------------------------------------
extern "C" void kernel_launch(void* const* d_in, const int* in_sizes, int n_in,
                              void* d_out, int out_size, void* d_ws, size_t ws_size,
                              hipStream_t stream)
{
    (void)in_sizes; (void)n_in; (void)out_size;

    const float* x  = (const float*)d_in[0];
    const float* Wq = (const float*)d_in[1];
    const float* bq = (const float*)d_in[2];
    const float* Wk = (const float*)d_in[3];
    const float* bk = (const float*)d_in[4];
    const float* Wv = (const float*)d_in[5];
    const float* bv = (const float*)d_in[6];
    const float* Wp = (const float*)d_in[7];
    const float* bp = (const float*)d_in[8];
    float* out = (float*)d_out;

    const size_t NN = 16777216;            // 4096*4096 elements
    const int n8 = (int)(NN / 8);
    dim3 cgrid((n8 + 255) / 256), cblk(256);
    dim3 ggrid(256), gblk(512);

    if (ws_size >= NN * 2 * 8) {
        // merged-cvt path: all 5 converts in one launch (needs 256 MB ws)
        uint16_t* xb  = (uint16_t*)d_ws;   // later reused as Y
        uint16_t* wqb = xb  + NN;
        uint16_t* wkb = wqb + NN;
        uint16_t* wvb = wkb + NN;
        uint16_t* wpb = wvb + NN;
        uint16_t* Qb  = wpb + NN;
        uint16_t* Kb  = Qb  + NN;
        uint16_t* Vb  = Kb  + NN;
        uint16_t* Yb  = xb;

        cvt5<<<dim3(8192 * 5), cblk, 0, stream>>>(x, Wq, Wk, Wv, Wp,
                                                  xb, wqb, wkb, wvb, wpb);
        gemm256<1><<<ggrid, gblk, 0, stream>>>(xb, wqb, bq, (void*)Qb, 4096, 4096, 4096);
        gemm256<1><<<ggrid, gblk, 0, stream>>>(xb, wkb, bk, (void*)Kb, 4096, 4096, 4096);
        gemm256<1><<<ggrid, gblk, 0, stream>>>(xb, wvb, bv, (void*)Vb, 4096, 4096, 4096);
        attn_kernel<<<dim3(4096), dim3(256), 0, stream>>>(Qb, Kb, Vb, Yb);
        gemm256<0><<<ggrid, gblk, 0, stream>>>(Yb, wpb, bp, (void*)out, 4096, 4096, 4096);
    } else {
        // sequential-wb fallback (160 MB ws)
        uint16_t* xb = (uint16_t*)d_ws;
        uint16_t* wb = xb + NN;
        uint16_t* Qb = wb + NN;
        uint16_t* Kb = Qb + NN;
        uint16_t* Vb = Kb + NN;
        uint16_t* Yb = xb;

        cvt_bf16<<<cgrid, cblk, 0, stream>>>(x, xb, n8);
        cvt_bf16<<<cgrid, cblk, 0, stream>>>(Wq, wb, n8);
        gemm256<1><<<ggrid, gblk, 0, stream>>>(xb, wb, bq, (void*)Qb, 4096, 4096, 4096);
        cvt_bf16<<<cgrid, cblk, 0, stream>>>(Wk, wb, n8);
        gemm256<1><<<ggrid, gblk, 0, stream>>>(xb, wb, bk, (void*)Kb, 4096, 4096, 4096);
        cvt_bf16<<<cgrid, cblk, 0, stream>>>(Wv, wb, n8);
        gemm256<1><<<ggrid, gblk, 0, stream>>>(xb, wb, bv, (void*)Vb, 4096, 4096, 4096);
        attn_kernel<<<dim3(4096), dim3(256), 0, stream>>>(Qb, Kb, Vb, Yb);
        cvt_bf16<<<cgrid, cblk, 0, stream>>>(Wp, wb, n8);
        gemm256<0><<<ggrid, gblk, 0, stream>>>(Yb, wb, bp, (void*)out, 4096, 4096, 4096);
    }
}